// Round 15
// baseline (930.494 us; speedup 1.0000x reference)
//
#include <hip/hip_runtime.h>

// ============================================================================
// CNF log-density, fused persistent kernel — v16: 3 independent blocks/SIMD.
//   - Diagnosis: v9-v15 all ~30% MfmaUtil at 2 waves/SIMD lockstep — pipes
//     SUM instead of overlap (wall ~= MFMA+VALU+LDS). Occupancy via a 128-reg
//     cap spills (v12); via same-block waves stays lockstep.
//   - NEW: block = 256 thr = 4 waves = ONE 16-row group (v13 fused val+tan
//     datapath, halved). LDS 40192B = 16KB 2-slot ring + tb 16.9KB + 3 slabs
//     -> 3 blocks/CU under launch_bounds(256,3) (reg cap 170 fits ~150 live).
//     Each SIMD hosts 3 waves from 3 UNSYNCED blocks -> real pipe interleave.
//   - 1-chunk phases (stage chunk G+1, compute G, 2 MFMA/wave); cyclic chunk
//     stream, slot = chunk&1 (40 even). Stage-after-barrier race-free.
//   - Layer 4: wave = (tile, kt-parity); partial sums via jb overlay (Pv/Pt
//     from kpar=1, combined + bias by kpar=0 -> dz slab + Jb), div row-reduce
//     by shfl (v12/v13 verified patterns).
// ============================================================================

#define DIM   64
#define HID   256
#define BATCH 32768
#define LOG2PI_HALF_SUM 58.8120661251f   // 32 * log(2*pi)

typedef float  floatx4  __attribute__((ext_vector_type(4)));
typedef float  floatx16 __attribute__((ext_vector_type(16)));
typedef short  short8   __attribute__((ext_vector_type(8)));

// ---- workspace: bf16 weights, fragment-linear, contiguous 40 x 8KB chunks --
// chunk c: W1 c0-3 (kt=c), W2 c4-19, W3 c20-35, W4 c36-39 (4kt x 2 tiles).
#define BOFF   327680    // biases fp32: b1[256] b2[256] b3[256] b4[64]
#define CHUNK  8192
#define NCHUNK 40

// ---- LDS ----
#define TBS         264              // shorts per tb row (256 + 8 pad)
#define TB_BYTES    16896            // 32 rows * 264 * 2
#define SLAB_STR    72               // shorts per slab row (64 + 8 pad)
#define SLAB_SH     1152             // shorts per slab (16*72)
#define RING_BYTES  16384            // 2 x 8KB chunk ring
#define SMEM_BYTES  (RING_BYTES + TB_BYTES + 3 * 2304)   // 40192 -> 3 blocks/CU
#define JBS 68                       // jb floats per row (64 + 4 pad)

#define MFMA32(a, b, c) __builtin_amdgcn_mfma_f32_32x32x16_bf16(a, b, c, 0, 0, 0)

__device__ __forceinline__ unsigned cvtpk(float lo, float hi) {
    unsigned r;
    asm("v_cvt_pk_bf16_f32 %0, %1, %2" : "=v"(r) : "v"(lo), "v"(hi));
    return r;
}

__device__ __forceinline__ float bf2f(short s) {
    union { float f; unsigned u; } v;
    v.u = ((unsigned)(unsigned short)s) << 16;
    return v.f;
}

__device__ __forceinline__ float fast_tanh(float x) {
    float e = __expf(2.0f * x);
    return 1.0f - 2.0f * __builtin_amdgcn_rcpf(e + 1.0f);
}

// ---- async global->LDS: 16B/lane, LDS dest = wave-uniform base + lane*16 ----
__device__ __forceinline__ void gld_lds16(const char* g, char* l) {
    __builtin_amdgcn_global_load_lds(
        (const __attribute__((address_space(1))) void*)g,
        (__attribute__((address_space(3))) void*)l, 16, 0, 0);
}

// Stage ws chunk g into ring slot g&1: each of 4 waves DMAs its 2KB slice.
__device__ __forceinline__ void stage_dma(const char* __restrict__ ws, char* ring,
                                          int g, int wave, int lane) {
    const char* src = ws + g * CHUNK + wave * 2048 + lane * 16;
    char* dst = ring + (g & 1) * CHUNK + wave * 2048;
    gld_lds16(src, dst);
    gld_lds16(src + 1024, dst + 1024);
}

// acc (2 ntl x 32 fused rows x 32 cols) -> tb: h rows 0-15, t rows 16-31.
__device__ __forceinline__ void transpose_acts(const floatx16 (&acc)[2],
                                               const float (&bv)[2], short* tb,
                                               int sw, int l31, int hi) {
    unsigned short* tbu = (unsigned short*)tb;
#pragma unroll
    for (int ntl = 0; ntl < 2; ntl++) {
        const int col = (sw * 2 + ntl) * 32 + l31;
#pragma unroll
        for (int p = 0; p < 4; p++) {
            const int r0 = 2 * p, r1 = r0 + 1;
            const int rv0 = (r0 & 3) + 8 * (r0 >> 2) + 4 * hi;
            const int rv1 = rv0 + 1;
            float h0 = fast_tanh(acc[ntl][r0] + bv[ntl]);
            float h1 = fast_tanh(acc[ntl][r1] + bv[ntl]);
            float t0 = __builtin_fmaf(-h0, h0, 1.0f) * acc[ntl][r0 + 8];
            float t1 = __builtin_fmaf(-h1, h1, 1.0f) * acc[ntl][r1 + 8];
            unsigned hp = cvtpk(h0, h1);
            unsigned tp = cvtpk(t0, t1);
            tbu[rv0 * TBS + col]        = (unsigned short)hp;
            tbu[rv1 * TBS + col]        = (unsigned short)(hp >> 16);
            tbu[(16 + rv0) * TBS + col] = (unsigned short)tp;
            tbu[(16 + rv1) * TBS + col] = (unsigned short)(tp >> 16);
        }
    }
}

// ---- one ODE f-eval: dz bf16 -> slab[sout]; returns div (all lanes) ----
__device__ __forceinline__ float feval(const float (&zs)[16], short8 e0, short8 e1,
                                       const char* __restrict__ ws, char* ring,
                                       short* tb, short* slabs, int sout,
                                       const floatx16& z16,
                                       const float (&b1r)[2], const float (&b2r)[2],
                                       const float (&b3r)[2], float b4v,
                                       int lane, int m, int kq, int sw,
                                       int l31, int hi, int wave) {
    // layer-1 A: wave 0 writes zs rows 0-15; wave 1 writes eps rows 16-31.
    if (sw == 0) {
        uint4 lo4 = { cvtpk(zs[0], zs[1]),   cvtpk(zs[2], zs[3]),
                      cvtpk(zs[4], zs[5]),   cvtpk(zs[6], zs[7]) };
        uint4 hi4 = { cvtpk(zs[8], zs[9]),   cvtpk(zs[10], zs[11]),
                      cvtpk(zs[12], zs[13]), cvtpk(zs[14], zs[15]) };
        *(uint4*)&tb[m * TBS + kq * 8]      = lo4;
        *(uint4*)&tb[m * TBS + 32 + kq * 8] = hi4;
    } else if (sw == 1) {
        *(short8*)&tb[(16 + m) * TBS + kq * 8]      = e0;
        *(short8*)&tb[(16 + m) * TBS + 32 + kq * 8] = e1;
    }

    floatx16 acc[2];

    // ---------- layer 1: phases G=0..3 (kt = G) ----------
#pragma unroll
    for (int G = 0; G < 4; G++) {
        __syncthreads();                         // chunk G + (G==0: inputs)
        stage_dma(ws, ring, G + 1, wave, lane);
        short8 a = *(const short8*)&tb[l31 * TBS + G * 16 + hi * 8];
        const char* bp = ring + (G & 1) * CHUNK;
        __builtin_amdgcn_s_setprio(1);
#pragma unroll
        for (int ntl = 0; ntl < 2; ntl++) {
            short8 b = *(const short8*)(bp + (sw * 2 + ntl) * 1024 + lane * 16);
            acc[ntl] = MFMA32(a, b, (G == 0) ? z16 : acc[ntl]);
        }
        __builtin_amdgcn_s_setprio(0);
    }
    __syncthreads();                             // tb input reads done
    transpose_acts(acc, b1r, tb, sw, l31, hi);   // published by next sync

    // ---------- layers 2,3: phases (chunks 4-19 / 20-35) ----------
#pragma unroll 1
    for (int layer = 0; layer < 2; layer++) {
        const int gb = 4 + layer * 16;
#pragma unroll
        for (int c = 0; c < 16; c++) {
            const int G = gb + c;
            __syncthreads();
            stage_dma(ws, ring, G + 1, wave, lane);   // max 36, no wrap
            short8 a = *(const short8*)&tb[l31 * TBS + c * 16 + hi * 8];
            const char* bp = ring + (G & 1) * CHUNK;
            __builtin_amdgcn_s_setprio(1);
#pragma unroll
            for (int ntl = 0; ntl < 2; ntl++) {
                short8 b = *(const short8*)(bp + (sw * 2 + ntl) * 1024 + lane * 16);
                acc[ntl] = MFMA32(a, b, (c == 0) ? z16 : acc[ntl]);
            }
            __builtin_amdgcn_s_setprio(0);
        }
        __syncthreads();                         // tb reads done
        transpose_acts(acc, layer ? b3r : b2r, tb, sw, l31, hi);
    }

    // ---------- layer 4: phases G=36..39; wave = (tile, kt-parity) ----------
    const int tile = sw & 1, kpar = sw >> 1;
    floatx16 a4;
#pragma unroll
    for (int c = 0; c < 4; c++) {
        const int G = 36 + c;
        const int nxt = (G + 1 == NCHUNK) ? 0 : G + 1;   // wrap: next feval
        __syncthreads();
        stage_dma(ws, ring, nxt, wave, lane);
        const char* bp = ring + (G & 1) * CHUNK;
        __builtin_amdgcn_s_setprio(1);
#pragma unroll
        for (int t = 0; t < 2; t++) {
            const int k4 = kpar + 2 * t;
            const int kt = c * 4 + k4;
            short8 a = *(const short8*)&tb[l31 * TBS + kt * 16 + hi * 8];
            short8 b = *(const short8*)(bp + (k4 * 2 + tile) * 1024 + lane * 16);
            a4 = (c == 0 && t == 0) ? MFMA32(a, b, z16) : MFMA32(a, b, a4);
        }
        __builtin_amdgcn_s_setprio(0);
    }
    __syncthreads();                             // tb A-reads done; overlay jb

    // ---- epilogue: kpar1 -> partials Pv/Pt; kpar0 -> dz slab + Jb; div ----
    float* Pv = (float*)tb;                      // [16][68] val partial (kpar1)
    float* Pt = (float*)tb + 16 * JBS;           // [16][68] tan partial (kpar1)
    float* Jb = (float*)tb + 32 * JBS;           // [16][68] final Jeps
    const int colp = tile * 32 + l31;
    if (kpar == 1) {
#pragma unroll
        for (int p = 0; p < 4; p++) {
            const int r0 = 2 * p, r1 = r0 + 1;
            const int rv0 = (r0 & 3) + 8 * (r0 >> 2) + 4 * hi;
            const int rv1 = rv0 + 1;
            Pv[rv0 * JBS + colp] = a4[r0];
            Pv[rv1 * JBS + colp] = a4[r1];
            Pt[rv0 * JBS + colp] = a4[r0 + 8];
            Pt[rv1 * JBS + colp] = a4[r1 + 8];
        }
    }
    __syncthreads();
    if (kpar == 0) {
        unsigned short* slu = (unsigned short*)(slabs + sout * SLAB_SH);
#pragma unroll
        for (int p = 0; p < 4; p++) {
            const int r0 = 2 * p, r1 = r0 + 1;
            const int rv0 = (r0 & 3) + 8 * (r0 >> 2) + 4 * hi;
            const int rv1 = rv0 + 1;
            float v0 = a4[r0] + Pv[rv0 * JBS + colp] + b4v;
            float v1 = a4[r1] + Pv[rv1 * JBS + colp] + b4v;
            unsigned dp = cvtpk(v0, v1);
            slu[rv0 * SLAB_STR + colp] = (unsigned short)dp;
            slu[rv1 * SLAB_STR + colp] = (unsigned short)(dp >> 16);
            Jb[rv0 * JBS + colp] = a4[r0 + 8] + Pt[rv0 * JBS + colp];
            Jb[rv1 * JBS + colp] = a4[r1 + 8] + Pt[rv1 * JBS + colp];
        }
    }
    __syncthreads();                             // Jb + slab visible
    float div = 0.f;
#pragma unroll
    for (int q = 0; q < 2; q++) {
        floatx4 j0 = *(const floatx4*)&Jb[m * JBS + kq * 8 + q * 4];
        floatx4 j1 = *(const floatx4*)&Jb[m * JBS + 32 + kq * 8 + q * 4];
#pragma unroll
        for (int j = 0; j < 4; j++)
            div += j0[j] * bf2f(e0[q * 4 + j]) + j1[j] * bf2f(e1[q * 4 + j]);
    }
    div += __shfl_xor(div, 16, 64);
    div += __shfl_xor(div, 32, 64);
    __syncthreads();                             // jb dead before next feval tb
    return div;
}

#define SLO(s) (*(const short8*)&slabs[(s) * SLAB_SH + m * SLAB_STR + kq * 8])
#define SHI(s) (*(const short8*)&slabs[(s) * SLAB_SH + m * SLAB_STR + 32 + kq * 8])

__global__ void __launch_bounds__(256, 3)
cnf_main(const float* __restrict__ x, const float* __restrict__ eps,
         const char* __restrict__ ws, float* __restrict__ out) {
    extern __shared__ char smem[];
    const int tid  = threadIdx.x;
    const int lane = tid & 63;
    const int wave = tid >> 6;
    const int sw   = wave;
    const int m = lane & 15, kq = lane >> 4;
    const int l31 = lane & 31, hi = lane >> 5;
    char*  ring  = smem;
    short* tb    = (short*)(smem + RING_BYTES);
    short* slabs = (short*)(smem + RING_BYTES + TB_BYTES);
    const int row = blockIdx.x * 16 + m;

    float y[16];
    short8 e0, e1;
#pragma unroll
    for (int kt = 0; kt < 2; kt++)
#pragma unroll
        for (int q = 0; q < 2; q++) {
            floatx4 vx = *(const floatx4*)(x   + row * DIM + kt * 32 + kq * 8 + q * 4);
            floatx4 ve = *(const floatx4*)(eps + row * DIM + kt * 32 + kq * 8 + q * 4);
#pragma unroll
            for (int j = 0; j < 4; j++) y[kt * 8 + q * 4 + j] = vx[j];
            unsigned p0 = cvtpk(ve[0], ve[1]), p1 = cvtpk(ve[2], ve[3]);
            if (kt == 0) { e0[q*4+0]=(short)p0; e0[q*4+1]=(short)(p0>>16);
                           e0[q*4+2]=(short)p1; e0[q*4+3]=(short)(p1>>16); }
            else         { e1[q*4+0]=(short)p0; e1[q*4+1]=(short)(p0>>16);
                           e1[q*4+2]=(short)p1; e1[q*4+3]=(short)(p1>>16); }
        }

    // persistent zero accumulator (C seed)
    floatx16 z16;
#pragma unroll
    for (int i = 0; i < 16; i++) z16[i] = 0.0f;

    // bias hoist: wave's cols = (sw*2+ntl)*32 + l31
    const float* bias = (const float*)(ws + BOFF);
    float b1r[2], b2r[2], b3r[2];
#pragma unroll
    for (int ntl = 0; ntl < 2; ntl++) {
        const int col = (sw * 2 + ntl) * 32 + l31;
        b1r[ntl] = bias[col];
        b2r[ntl] = bias[256 + col];
        b3r[ntl] = bias[512 + col];
    }
    const float b4v = bias[768 + (sw & 1) * 32 + l31];

    // zero slabs (0-coeff combines must not FMA garbage)
    {
        short8 z = {0, 0, 0, 0, 0, 0, 0, 0};
        for (int k = tid; k < 432; k += 256) *(short8*)&slabs[k * 8] = z;
    }

    // prologue: stage chunk 0 (first feval's phase-0 sync publishes it)
    stage_dma(ws, ring, 0, wave, lane);

    float ylogp = 0.f;
    short8 zero8 = {0, 0, 0, 0, 0, 0, 0, 0};
    short8 k1a = zero8, k1b = zero8, k3a = zero8, k3b = zero8;

#pragma unroll 1
    for (int st = 0; st < 24; st++) {
        const int stage = st % 6;
        float c1, c2, c3, c4, c5, bw; int sout;
        switch (stage) {
            case 0: c1=0.f;           c2=0.f;            c3=0.f;           c4=0.f;            c5=0.f;            bw=0.022786458f;  sout=0; break;
            case 1: c1=0.05f;         c2=0.f;            c3=0.f;           c4=0.f;            c5=0.f;            bw=0.f;           sout=0; break;
            case 2: c1=0.01875f;      c2=0.05625f;       c3=0.f;           c4=0.f;            c5=0.f;            bw=0.112309075f;  sout=1; break;
            case 3: c1=0.244444444f;  c2=-0.933333333f;  c3=0.888888889f;  c4=0.f;            c5=0.f;            bw=0.162760417f;  sout=1; break;
            case 4: c1=0.738149672f;  c2=-2.898948331f;  c3=2.455723213f;  c4=-0.072702332f;  c5=0.f;            bw=-0.080593989f; sout=2; break;
            default:c1=0.711568813f;  c2=-2.689393939f;  c3=2.226605679f;  c4=0.069602273f;   c5=-0.068382826f;  bw=0.032738095f;  sout=0; break;
        }

        // zs = y + c1 k1(regs) + c2 slab0 + c3 k3(regs) + c4 slab1 + c5 slab2
        float zs[16];
        {
            short8 k2a = SLO(0), k2b = SHI(0);
            short8 k4a = SLO(1), k4b = SHI(1);
            short8 k5a = SLO(2), k5b = SHI(2);
#pragma unroll
            for (int j = 0; j < 8; j++) {
                zs[j]     = y[j]     + c1 * bf2f(k1a[j]) + c2 * bf2f(k2a[j])
                                     + c3 * bf2f(k3a[j]) + c4 * bf2f(k4a[j])
                                     + c5 * bf2f(k5a[j]);
                zs[8 + j] = y[8 + j] + c1 * bf2f(k1b[j]) + c2 * bf2f(k2b[j])
                                     + c3 * bf2f(k3b[j]) + c4 * bf2f(k4b[j])
                                     + c5 * bf2f(k5b[j]);
            }
        }

        const float d = feval(zs, e0, e1, ws, ring, tb, slabs, sout, z16,
                              b1r, b2r, b3r, b4v,
                              lane, m, kq, sw, l31, hi, wave);

        if (stage == 0) { k1a = SLO(0); k1b = SHI(0); }   // k1 -> regs (slot 0 -> k2)
        if (stage == 2) { k3a = SLO(1); k3b = SHI(1); }   // k3 -> regs (slot 1 -> k4)
        if (stage == 5) {
            // y += b1 k1 + b3 k3 + b4 slab1 + b5 slab2 + b6 slab0
            short8 k4a = SLO(1), k4b = SHI(1);
            short8 k5a = SLO(2), k5b = SHI(2);
            short8 k6a = SLO(0), k6b = SHI(0);
#pragma unroll
            for (int j = 0; j < 8; j++) {
                y[j]     += 0.022786458f * bf2f(k1a[j]) + 0.112309075f * bf2f(k3a[j])
                          + 0.162760417f * bf2f(k4a[j]) - 0.080593989f * bf2f(k5a[j])
                          + 0.032738095f * bf2f(k6a[j]);
                y[8 + j] += 0.022786458f * bf2f(k1b[j]) + 0.112309075f * bf2f(k3b[j])
                          + 0.162760417f * bf2f(k4b[j]) - 0.080593989f * bf2f(k5b[j])
                          + 0.032738095f * bf2f(k6b[j]);
            }
        }
        ylogp -= bw * d;
    }

    float nrm = 0.f;
#pragma unroll
    for (int i = 0; i < 16; i++) nrm += y[i] * y[i];
    nrm += __shfl_xor(nrm, 16, 64);
    nrm += __shfl_xor(nrm, 32, 64);
    float res = -0.5f * nrm - LOG2PI_HALF_SUM - ylogp;
    asm volatile("s_waitcnt vmcnt(0)" ::: "memory");   // retire dangling prefetch
    if (sw == 0 && lane < 16) out[blockIdx.x * 16 + lane] = res;
}

// ---- weight pre-shuffle: fp32 [N][K] -> bf16 fragment-linear (32x32x16) ----
// frag = ktile*NT + ntile; lane l holds W[ntile*32 + (l&31)][ktile*16 + (l>>5)*8 + 0..7]
__global__ void prep_w(const float* __restrict__ W, short* __restrict__ outp,
                       int K, int NT, int KT) {
    int slot  = blockIdx.x * 256 + threadIdx.x;
    int total = KT * NT * 64;
    if (slot >= total) return;
    int lane  = slot & 63, frag = slot >> 6;
    int ntile = frag % NT, ktile = frag / NT;
    int n = ntile * 32 + (lane & 31);
    int k = ktile * 16 + (lane >> 5) * 8;
    short8 v;
#pragma unroll
    for (int j = 0; j < 8; j++) {
        union { float f; unsigned u; } w; w.f = W[n * K + k + j];
        unsigned r = w.u + 0x7FFFu + ((w.u >> 16) & 1u);
        v[j] = (short)(r >> 16);
    }
    *(short8*)(outp + slot * 8) = v;
}

__global__ void prep_b(const float* __restrict__ b1, const float* __restrict__ b2,
                       const float* __restrict__ b3, const float* __restrict__ b4,
                       float* __restrict__ dst) {
    int i = blockIdx.x * 256 + threadIdx.x;
    if (i < 256)      dst[i] = b1[i];
    else if (i < 512) dst[i] = b2[i - 256];
    else if (i < 768) dst[i] = b3[i - 512];
    else if (i < 832) dst[i] = b4[i - 768];
}

extern "C" void kernel_launch(void* const* d_in, const int* in_sizes, int n_in,
                              void* d_out, int out_size, void* d_ws, size_t ws_size,
                              hipStream_t stream) {
    const float* x   = (const float*)d_in[0];
    const float* eps = (const float*)d_in[1];
    const float* W1  = (const float*)d_in[2];
    const float* b1  = (const float*)d_in[3];
    const float* W2  = (const float*)d_in[4];
    const float* b2  = (const float*)d_in[5];
    const float* W3  = (const float*)d_in[6];
    const float* b3  = (const float*)d_in[7];
    const float* W4  = (const float*)d_in[8];
    const float* b4  = (const float*)d_in[9];
    char*  ws  = (char*)d_ws;
    float* out = (float*)d_out;

    // W1: KT=4, NT=8  -> 32 frags  @ ws+0       (32KB,  chunks 0-3)
    // W2: KT=16,NT=8  -> 128 frags @ ws+32768   (128KB, chunks 4-19)
    // W3: KT=16,NT=8  -> 128 frags @ ws+163840  (128KB, chunks 20-35)
    // W4: KT=16,NT=2  -> 32 frags  @ ws+294912  (32KB,  chunks 36-39)
    prep_w<<<8,  256, 0, stream>>>(W1, (short*)(ws + 0),      64,  8, 4);
    prep_w<<<32, 256, 0, stream>>>(W2, (short*)(ws + 32768),  256, 8, 16);
    prep_w<<<32, 256, 0, stream>>>(W3, (short*)(ws + 163840), 256, 8, 16);
    prep_w<<<8,  256, 0, stream>>>(W4, (short*)(ws + 294912), 256, 2, 16);
    prep_b<<<4, 256, 0, stream>>>(b1, b2, b3, b4, (float*)(ws + BOFF));

    cnf_main<<<BATCH / 16, 256, SMEM_BYTES, stream>>>(x, eps, ws, out);
}

// Round 16
// 714.371 us; speedup vs baseline: 1.3025x; 1.3025x over previous
//
#include <hip/hip_runtime.h>

// ============================================================================
// CNF log-density, fused persistent kernel — v17 = v14 (best verified, 715us).
//   Final configuration after 16 measured rounds. Design points, each pinned
//   by a counter-verified experiment:
//   - 512 thr = 8 waves = 4 row-groups x (2-wave N-split); 2 waves/SIMD.
//     (v12: 4 waves/SIMD reg-cap -> spill -> L2 poison, 1507us.
//      v16: 3 independent blocks/SIMD -> 44 tiny barriers, 930us.)
//   - Weights streamed as 40 x 8KB fragment-linear chunks via global_load_lds
//     DMA into an 8-slot LDS ring; stage-after-barrier; 4-chunk phases with
//     plain __syncthreads (v7 ring: 774us breakthrough; v13 dropped
//     sched_barrier pins + acc-init movs: 720us).
//   - 32x32x16 MFMA, A rows 0-15 = value / 16-31 = tangent: one MFMA computes
//     both GEMMs (halves MFMA count + B-reads vs 16x16 split).
//   - Transpose split T_A/T_B interleaved into adjacent MFMA phases via
//     commutative kt reordering (v14).
//   - RK: flattened 24-stage machine; k1/k3 bf16 in regs, k2/k4/k5/k6 in
//     3 group-private bf16 LDS slabs; cvt_pk bf16 packing; bias hoist.
//   - Zero spill (WRITE_SIZE 128KB) is the binding invariant: every spill
//     event (v2/v3/v8/v12) poisoned L2 and sent the 24x weight re-stream to
//     HBM. FETCH ~9.6MB/dispatch = weights fully L2-resident.
// ============================================================================

#define DIM   64
#define HID   256
#define BATCH 32768
#define LOG2PI_HALF_SUM 58.8120661251f   // 32 * log(2*pi)

typedef float  floatx4  __attribute__((ext_vector_type(4)));
typedef float  floatx16 __attribute__((ext_vector_type(16)));
typedef short  short8   __attribute__((ext_vector_type(8)));

// ---- workspace: bf16 weights, fragment-linear, contiguous 40 x 8KB chunks --
// ws chunk c: W1 c0-3 (kt=c), W2 c4-19 (kt=c-4), W3 c20-35, W4 c36-39 (4kt).
#define BOFF   327680    // biases fp32: b1[256] b2[256] b3[256] b4[64]
#define CHUNK  8192
#define NCHUNK 40

// ---- LDS ----
#define TBS         264              // shorts per tb row (256 + 8 pad)
#define TB_BYTES    16896            // 32 * 264 * 2
#define SLAB_STR    72               // shorts per slab row (64 + 8 pad)
#define SLAB_SH     1152             // shorts per slab (16*72)
#define RING_BYTES  65536            // 8 x 8KB chunk ring
#define GROUP_BYTES 23808            // tb + 3 slabs (16896 + 6912)
#define SMEM_BYTES  (RING_BYTES + 4 * GROUP_BYTES)   // 160768 -> 1 block/CU

#define MFMA32(a, b, c) __builtin_amdgcn_mfma_f32_32x32x16_bf16(a, b, c, 0, 0, 0)

__device__ __forceinline__ unsigned cvtpk(float lo, float hi) {
    unsigned r;
    asm("v_cvt_pk_bf16_f32 %0, %1, %2" : "=v"(r) : "v"(lo), "v"(hi));
    return r;
}

__device__ __forceinline__ float bf2f(short s) {
    union { float f; unsigned u; } v;
    v.u = ((unsigned)(unsigned short)s) << 16;
    return v.f;
}

__device__ __forceinline__ float fast_tanh(float x) {
    float e = __expf(2.0f * x);
    return 1.0f - 2.0f * __builtin_amdgcn_rcpf(e + 1.0f);
}

// ---- async global->LDS: 16B/lane, LDS dest = wave-uniform base + lane*16 ----
__device__ __forceinline__ void gld_lds16(const char* g, char* l) {
    __builtin_amdgcn_global_load_lds(
        (const __attribute__((address_space(1))) void*)g,
        (__attribute__((address_space(3))) void*)l, 16, 0, 0);
}

// Stage ws chunk g into ring slot `slot`: each of 8 waves DMAs its 1KB slice.
__device__ __forceinline__ void stage_dma(const char* __restrict__ ws, char* ring,
                                          int g, int slot, int wave, int lane) {
    const char* src = ws + g * CHUNK + wave * 1024 + lane * 16;
    char* dst = ring + slot * CHUNK + wave * 1024;
    gld_lds16(src, dst);
}

// One nt-column-block (32 cols) of acc -> tb (h rows 0-15, t rows 16-31).
// Bias folds into the tanh argument; tangent rows are bias-free.
__device__ __forceinline__ void transpose_nt(const floatx16& a, float bv, short* tb,
                                             int nt, int sw, int l31, int hi) {
    unsigned short* tbu = (unsigned short*)tb;
    const int col = sw * 128 + nt * 32 + l31;
#pragma unroll
    for (int p = 0; p < 4; p++) {
        const int r0 = 2 * p, r1 = r0 + 1;
        const int rv0 = (r0 & 3) + 8 * (r0 >> 2) + 4 * hi;
        const int rv1 = rv0 + 1;
        float h0 = fast_tanh(a[r0] + bv);
        float h1 = fast_tanh(a[r1] + bv);
        float t0 = __builtin_fmaf(-h0, h0, 1.0f) * a[r0 + 8];
        float t1 = __builtin_fmaf(-h1, h1, 1.0f) * a[r1 + 8];
        unsigned hp = cvtpk(h0, h1);
        unsigned tp = cvtpk(t0, t1);
        tbu[rv0 * TBS + col]        = (unsigned short)hp;
        tbu[rv1 * TBS + col]        = (unsigned short)(hp >> 16);
        tbu[(16 + rv0) * TBS + col] = (unsigned short)tp;
        tbu[(16 + rv1) * TBS + col] = (unsigned short)(tp >> 16);
    }
}

// Hidden layer (K=256, 16 ws chunks at GB, stream base SB). Phase pp consumes
// kt-group KTB[pp]; T_B of the previous layer's acc runs in phases 0-1; T_A of
// this layer's acc runs in phase 3 (its target cols were last read 3 barriers
// earlier). nxt = ws chunks staged during phase 3 (next layer's first group).
template<int GB, int SB>
__device__ __forceinline__ void hid_layer(const char* __restrict__ ws, char* ring,
                                          short* tb,
                                          const floatx16& p2, const floatx16& p3,
                                          float pb2, float pb3,
                                          floatx16 (&acc)[4], float ob0, float ob1,
                                          const floatx16& z16, const int (&nxt)[4],
                                          int wave, int lane, int sw,
                                          int l31, int hi) {
    constexpr int KTB[4] = {0, 8, 4, 12};
#pragma unroll
    for (int pp = 0; pp < 4; pp++) {
        __syncthreads();
#pragma unroll
        for (int i = 0; i < 4; i++) {
            const int wsn  = (pp < 3) ? (GB + KTB[pp + 1] + i) : nxt[i];
            stage_dma(ws, ring, wsn, (SB + pp * 4 + 4 + i) & 7, wave, lane);
        }
        if (pp == 0) transpose_nt(p2, pb2, tb, 2, sw, l31, hi);
        if (pp == 1) transpose_nt(p3, pb3, tb, 3, sw, l31, hi);
#pragma unroll
        for (int cc = 0; cc < 4; cc++) {
            const int kt   = KTB[pp] + cc;
            const int slot = (SB + pp * 4 + cc) & 7;
            short8 a = *(const short8*)&tb[l31 * TBS + kt * 16 + hi * 8];
            const char* bp = ring + slot * CHUNK;
            __builtin_amdgcn_s_setprio(1);
#pragma unroll
            for (int nt = 0; nt < 4; nt++) {
                short8 b = *(const short8*)(bp + (sw * 4 + nt) * 1024 + lane * 16);
                acc[nt] = MFMA32(a, b, (pp == 0 && cc == 0) ? z16 : acc[nt]);
            }
            __builtin_amdgcn_s_setprio(0);
        }
        if (pp == 3) {
            transpose_nt(acc[0], ob0, tb, 0, sw, l31, hi);
            transpose_nt(acc[1], ob1, tb, 1, sw, l31, hi);
        }
    }
}

// ---- one ODE f-eval: dz bf16 -> slab[sout]; returns div (all lanes) ----
__device__ __forceinline__ float feval(const float (&zs)[16], short8 e0, short8 e1,
                                       const char* __restrict__ ws, char* ring,
                                       short* tb, short* slabs, int sout,
                                       const floatx16& z16,
                                       const float (&b1r)[4], const float (&b2r)[4],
                                       const float (&b3r)[4], float b4v,
                                       int lane, int m, int kq, int sw,
                                       int l31, int hi, int wave) {
    float* jb = (float*)tb;                       // overlays tb rows 0-8

    // layer-1 A: sw0 writes zs rows 0-15; sw1 writes eps rows 16-31.
    if (sw == 0) {
        uint4 lo4 = { cvtpk(zs[0], zs[1]),   cvtpk(zs[2], zs[3]),
                      cvtpk(zs[4], zs[5]),   cvtpk(zs[6], zs[7]) };
        uint4 hi4 = { cvtpk(zs[8], zs[9]),   cvtpk(zs[10], zs[11]),
                      cvtpk(zs[12], zs[13]), cvtpk(zs[14], zs[15]) };
        *(uint4*)&tb[m * TBS + kq * 8]      = lo4;
        *(uint4*)&tb[m * TBS + 32 + kq * 8] = hi4;
    } else {
        *(short8*)&tb[(16 + m) * TBS + kq * 8]      = e0;
        *(short8*)&tb[(16 + m) * TBS + 32 + kq * 8] = e1;
    }

    floatx16 acc[4], acc2[4];

    // ---------- layer 1 (stream 0-3 = ws 0-3): read, stage ws 4-7 ----------
    __syncthreads();                       // input + ws 0-3 DMAs visible
#pragma unroll
    for (int i = 0; i < 4; i++) stage_dma(ws, ring, 4 + i, 4 + i, wave, lane);
#pragma unroll
    for (int G = 0; G < 4; G++) {
        short8 a = *(const short8*)&tb[l31 * TBS + G * 16 + hi * 8];
        const char* bp = ring + G * CHUNK;
        __builtin_amdgcn_s_setprio(1);
#pragma unroll
        for (int nt = 0; nt < 4; nt++) {
            short8 b = *(const short8*)(bp + (sw * 4 + nt) * 1024 + lane * 16);
            acc[nt] = MFMA32(a, b, (G == 0) ? z16 : acc[nt]);
        }
        __builtin_amdgcn_s_setprio(0);
    }
    __syncthreads();                       // all tb input reads done
    transpose_nt(acc[0], b1r[0], tb, 0, sw, l31, hi);   // T_A of layer 1
    transpose_nt(acc[1], b1r[1], tb, 1, sw, l31, hi);

    // ---------- layers 2,3 ----------
    const int nxt2[4] = {20, 21, 22, 23};
    const int nxt3[4] = {36, 38, 37, 39};
    hid_layer<4, 4>(ws, ring, tb, acc[2], acc[3], b1r[2], b1r[3],
                    acc2, b2r[0], b2r[1], z16, nxt2, wave, lane, sw, l31, hi);
    hid_layer<20, 20>(ws, ring, tb, acc2[2], acc2[3], b2r[2], b2r[3],
                      acc, b3r[0], b3r[1], z16, nxt3, wave, lane, sw, l31, hi);

    // ---------- layer 4: phaseA (stream 36-37 = ws 36,38), T_B inside ------
    floatx16 a4;
    __syncthreads();
    stage_dma(ws, ring, 0, 0, wave, lane);         // next feval stream 40-41
    stage_dma(ws, ring, 1, 1, wave, lane);
    transpose_nt(acc[2], b3r[2], tb, 2, sw, l31, hi);
    transpose_nt(acc[3], b3r[3], tb, 3, sw, l31, hi);
#pragma unroll
    for (int j2 = 0; j2 < 2; j2++) {
        const int ktb = j2 ? 8 : 0;
        const char* bp = ring + (4 + j2) * CHUNK;  // slots 4,5 = ws 36,38
        __builtin_amdgcn_s_setprio(1);
#pragma unroll
        for (int k4 = 0; k4 < 4; k4++) {
            short8 a = *(const short8*)&tb[l31 * TBS + (ktb + k4) * 16 + hi * 8];
            short8 b = *(const short8*)(bp + (k4 * 2 + sw) * 1024 + lane * 16);
            a4 = (j2 == 0 && k4 == 0) ? MFMA32(a, b, z16) : MFMA32(a, b, a4);
        }
        __builtin_amdgcn_s_setprio(0);
    }

    // ---------- layer 4: phaseB (stream 38-39 = ws 37,39) ----------
    __syncthreads();                                // publishes T_B
    stage_dma(ws, ring, 2, 2, wave, lane);          // next feval stream 42-43
    stage_dma(ws, ring, 3, 3, wave, lane);
#pragma unroll
    for (int j2 = 0; j2 < 2; j2++) {
        const int ktb = j2 ? 12 : 4;
        const char* bp = ring + (6 + j2) * CHUNK;   // slots 6,7 = ws 37,39
        __builtin_amdgcn_s_setprio(1);
#pragma unroll
        for (int k4 = 0; k4 < 4; k4++) {
            short8 a = *(const short8*)&tb[l31 * TBS + (ktb + k4) * 16 + hi * 8];
            short8 b = *(const short8*)(bp + (k4 * 2 + sw) * 1024 + lane * 16);
            a4 = MFMA32(a, b, a4);
        }
        __builtin_amdgcn_s_setprio(0);
    }
#pragma unroll
    for (int r = 0; r < 8; r++) a4[r] += b4v;      // val rows only
    __syncthreads();                       // tb A-reads done; overlay jb

    // ---- epilogue: Jeps fp32 -> jb; dz bf16 (cvt_pk pairs) -> slab[sout] ----
    unsigned short* slu = (unsigned short*)(slabs + sout * SLAB_SH);
#pragma unroll
    for (int p = 0; p < 4; p++) {
        const int r0 = 2 * p, r1 = r0 + 1;
        const int rv0 = (r0 & 3) + 8 * (r0 >> 2) + 4 * hi;
        const int rv1 = rv0 + 1;
        jb[rv0 * 68 + sw * 32 + l31] = a4[r0 + 8];
        jb[rv1 * 68 + sw * 32 + l31] = a4[r1 + 8];
        unsigned dp = cvtpk(a4[r0], a4[r1]);
        slu[rv0 * SLAB_STR + sw * 32 + l31] = (unsigned short)dp;
        slu[rv1 * SLAB_STR + sw * 32 + l31] = (unsigned short)(dp >> 16);
    }
    __syncthreads();                       // jb + slab visible
    float div = 0.f;
#pragma unroll
    for (int q = 0; q < 2; q++) {
        floatx4 j0 = *(const floatx4*)&jb[m * 68 + kq * 8 + q * 4];
        floatx4 j1 = *(const floatx4*)&jb[m * 68 + 32 + kq * 8 + q * 4];
#pragma unroll
        for (int j = 0; j < 4; j++)
            div += j0[j] * bf2f(e0[q * 4 + j]) + j1[j] * bf2f(e1[q * 4 + j]);
    }
    div += __shfl_xor(div, 16, 64);
    div += __shfl_xor(div, 32, 64);
    __syncthreads();                       // jb dead before next feval's tb
    return div;
}

#define SLO(s) (*(const short8*)&slabs[(s) * SLAB_SH + m * SLAB_STR + kq * 8])
#define SHI(s) (*(const short8*)&slabs[(s) * SLAB_SH + m * SLAB_STR + 32 + kq * 8])

__global__ void __launch_bounds__(512, 2)
cnf_main(const float* __restrict__ x, const float* __restrict__ eps,
         const char* __restrict__ ws, float* __restrict__ out) {
    extern __shared__ char smem[];
    const int tid  = threadIdx.x;
    const int lane = tid & 63;
    const int wave = tid >> 6;
    const int group = wave >> 1, sw = wave & 1;
    const int m = lane & 15, kq = lane >> 4;
    const int l31 = lane & 31, hi = lane >> 5;
    char*  ring  = smem;
    short* tb    = (short*)(smem + RING_BYTES + group * GROUP_BYTES);
    short* slabs = (short*)(smem + RING_BYTES + group * GROUP_BYTES + TB_BYTES);
    const int row = blockIdx.x * 64 + group * 16 + m;

    float y[16];
    short8 e0, e1;
#pragma unroll
    for (int kt = 0; kt < 2; kt++)
#pragma unroll
        for (int q = 0; q < 2; q++) {
            floatx4 vx = *(const floatx4*)(x   + row * DIM + kt * 32 + kq * 8 + q * 4);
            floatx4 ve = *(const floatx4*)(eps + row * DIM + kt * 32 + kq * 8 + q * 4);
#pragma unroll
            for (int j = 0; j < 4; j++) y[kt * 8 + q * 4 + j] = vx[j];
            unsigned p0 = cvtpk(ve[0], ve[1]), p1 = cvtpk(ve[2], ve[3]);
            if (kt == 0) { e0[q*4+0]=(short)p0; e0[q*4+1]=(short)(p0>>16);
                           e0[q*4+2]=(short)p1; e0[q*4+3]=(short)(p1>>16); }
            else         { e1[q*4+0]=(short)p0; e1[q*4+1]=(short)(p0>>16);
                           e1[q*4+2]=(short)p1; e1[q*4+3]=(short)(p1>>16); }
        }

    // persistent zero accumulator (C seed; kills per-layer acc-init movs)
    floatx16 z16;
#pragma unroll
    for (int i = 0; i < 16; i++) z16[i] = 0.0f;

    // bias hoist: 13 persistent regs
    const float* bias = (const float*)(ws + BOFF);
    float b1r[4], b2r[4], b3r[4];
#pragma unroll
    for (int nt = 0; nt < 4; nt++) {
        const int col = sw * 128 + nt * 32 + l31;
        b1r[nt] = bias[col];
        b2r[nt] = bias[256 + col];
        b3r[nt] = bias[512 + col];
    }
    const float b4v = bias[768 + sw * 32 + l31];

    // zero all groups' slabs (0-coeff combines must not FMA NaN garbage)
    {
        short8 z = {0, 0, 0, 0, 0, 0, 0, 0};
#pragma unroll
        for (int g = 0; g < 4; g++) {
            short* sb = (short*)(smem + RING_BYTES + g * GROUP_BYTES + TB_BYTES);
            for (int k = tid; k < 432; k += 512) *(short8*)&sb[k * 8] = z;
        }
    }

    // prologue: stage stream 0-3 (ws 0-3, slots 0-3)
#pragma unroll
    for (int s = 0; s < 4; s++) stage_dma(ws, ring, s, s, wave, lane);

    float ylogp = 0.f;
    short8 zero8 = {0, 0, 0, 0, 0, 0, 0, 0};
    short8 k1a = zero8, k1b = zero8, k3a = zero8, k3b = zero8;

#pragma unroll 1
    for (int st = 0; st < 24; st++) {
        const int stage = st % 6;
        float c1, c2, c3, c4, c5, bw; int sout;
        switch (stage) {
            case 0: c1=0.f;           c2=0.f;            c3=0.f;           c4=0.f;            c5=0.f;            bw=0.022786458f;  sout=0; break;
            case 1: c1=0.05f;         c2=0.f;            c3=0.f;           c4=0.f;            c5=0.f;            bw=0.f;           sout=0; break;
            case 2: c1=0.01875f;      c2=0.05625f;       c3=0.f;           c4=0.f;            c5=0.f;            bw=0.112309075f;  sout=1; break;
            case 3: c1=0.244444444f;  c2=-0.933333333f;  c3=0.888888889f;  c4=0.f;            c5=0.f;            bw=0.162760417f;  sout=1; break;
            case 4: c1=0.738149672f;  c2=-2.898948331f;  c3=2.455723213f;  c4=-0.072702332f;  c5=0.f;            bw=-0.080593989f; sout=2; break;
            default:c1=0.711568813f;  c2=-2.689393939f;  c3=2.226605679f;  c4=0.069602273f;   c5=-0.068382826f;  bw=0.032738095f;  sout=0; break;
        }

        // zs = y + c1 k1(regs) + c2 slab0 + c3 k3(regs) + c4 slab1 + c5 slab2
        float zs[16];
        {
            short8 k2a = SLO(0), k2b = SHI(0);
            short8 k4a = SLO(1), k4b = SHI(1);
            short8 k5a = SLO(2), k5b = SHI(2);
#pragma unroll
            for (int j = 0; j < 8; j++) {
                zs[j]     = y[j]     + c1 * bf2f(k1a[j]) + c2 * bf2f(k2a[j])
                                     + c3 * bf2f(k3a[j]) + c4 * bf2f(k4a[j])
                                     + c5 * bf2f(k5a[j]);
                zs[8 + j] = y[8 + j] + c1 * bf2f(k1b[j]) + c2 * bf2f(k2b[j])
                                     + c3 * bf2f(k3b[j]) + c4 * bf2f(k4b[j])
                                     + c5 * bf2f(k5b[j]);
            }
        }

        const float d = feval(zs, e0, e1, ws, ring, tb, slabs, sout, z16,
                              b1r, b2r, b3r, b4v,
                              lane, m, kq, sw, l31, hi, wave);

        if (stage == 0) { k1a = SLO(0); k1b = SHI(0); }   // k1 -> regs (slot 0 -> k2)
        if (stage == 2) { k3a = SLO(1); k3b = SHI(1); }   // k3 -> regs (slot 1 -> k4)
        if (stage == 5) {
            // y += b1 k1 + b3 k3 + b4 slab1 + b5 slab2 + b6 slab0
            short8 k4a = SLO(1), k4b = SHI(1);
            short8 k5a = SLO(2), k5b = SHI(2);
            short8 k6a = SLO(0), k6b = SHI(0);
#pragma unroll
            for (int j = 0; j < 8; j++) {
                y[j]     += 0.022786458f * bf2f(k1a[j]) + 0.112309075f * bf2f(k3a[j])
                          + 0.162760417f * bf2f(k4a[j]) - 0.080593989f * bf2f(k5a[j])
                          + 0.032738095f * bf2f(k6a[j]);
                y[8 + j] += 0.022786458f * bf2f(k1b[j]) + 0.112309075f * bf2f(k3b[j])
                          + 0.162760417f * bf2f(k4b[j]) - 0.080593989f * bf2f(k5b[j])
                          + 0.032738095f * bf2f(k6b[j]);
            }
        }
        ylogp -= bw * d;
    }

    float nrm = 0.f;
#pragma unroll
    for (int i = 0; i < 16; i++) nrm += y[i] * y[i];
    nrm += __shfl_xor(nrm, 16, 64);
    nrm += __shfl_xor(nrm, 32, 64);
    float res = -0.5f * nrm - LOG2PI_HALF_SUM - ylogp;
    if (sw == 0 && lane < 16) out[blockIdx.x * 64 + group * 16 + lane] = res;
}

// ---- weight pre-shuffle: fp32 [N][K] -> bf16 fragment-linear (32x32x16) ----
// frag = ktile*NT + ntile; lane l holds W[ntile*32 + (l&31)][ktile*16 + (l>>5)*8 + 0..7]
__global__ void prep_w(const float* __restrict__ W, short* __restrict__ outp,
                       int K, int NT, int KT) {
    int slot  = blockIdx.x * 256 + threadIdx.x;
    int total = KT * NT * 64;
    if (slot >= total) return;
    int lane  = slot & 63, frag = slot >> 6;
    int ntile = frag % NT, ktile = frag / NT;
    int n = ntile * 32 + (lane & 31);
    int k = ktile * 16 + (lane >> 5) * 8;
    short8 v;
#pragma unroll
    for (int j = 0; j < 8; j++) {
        union { float f; unsigned u; } w; w.f = W[n * K + k + j];
        unsigned r = w.u + 0x7FFFu + ((w.u >> 16) & 1u);
        v[j] = (short)(r >> 16);
    }
    *(short8*)(outp + slot * 8) = v;
}

__global__ void prep_b(const float* __restrict__ b1, const float* __restrict__ b2,
                       const float* __restrict__ b3, const float* __restrict__ b4,
                       float* __restrict__ dst) {
    int i = blockIdx.x * 256 + threadIdx.x;
    if (i < 256)      dst[i] = b1[i];
    else if (i < 512) dst[i] = b2[i - 256];
    else if (i < 768) dst[i] = b3[i - 512];
    else if (i < 832) dst[i] = b4[i - 768];
}

extern "C" void kernel_launch(void* const* d_in, const int* in_sizes, int n_in,
                              void* d_out, int out_size, void* d_ws, size_t ws_size,
                              hipStream_t stream) {
    const float* x   = (const float*)d_in[0];
    const float* eps = (const float*)d_in[1];
    const float* W1  = (const float*)d_in[2];
    const float* b1  = (const float*)d_in[3];
    const float* W2  = (const float*)d_in[4];
    const float* b2  = (const float*)d_in[5];
    const float* W3  = (const float*)d_in[6];
    const float* b3  = (const float*)d_in[7];
    const float* W4  = (const float*)d_in[8];
    const float* b4  = (const float*)d_in[9];
    char*  ws  = (char*)d_ws;
    float* out = (float*)d_out;

    static bool attr_set = false;
    if (!attr_set) {
        hipFuncSetAttribute(reinterpret_cast<const void*>(cnf_main),
                            hipFuncAttributeMaxDynamicSharedMemorySize, SMEM_BYTES);
        attr_set = true;
    }

    // W1: KT=4, NT=8  -> 32 frags  @ ws+0       (32KB,  chunks 0-3)
    // W2: KT=16,NT=8  -> 128 frags @ ws+32768   (128KB, chunks 4-19)
    // W3: KT=16,NT=8  -> 128 frags @ ws+163840  (128KB, chunks 20-35)
    // W4: KT=16,NT=2  -> 32 frags  @ ws+294912  (32KB,  chunks 36-39)
    prep_w<<<8,  256, 0, stream>>>(W1, (short*)(ws + 0),      64,  8, 4);
    prep_w<<<32, 256, 0, stream>>>(W2, (short*)(ws + 32768),  256, 8, 16);
    prep_w<<<32, 256, 0, stream>>>(W3, (short*)(ws + 163840), 256, 8, 16);
    prep_w<<<8,  256, 0, stream>>>(W4, (short*)(ws + 294912), 256, 2, 16);
    prep_b<<<4, 256, 0, stream>>>(b1, b2, b3, b4, (float*)(ws + BOFF));

    cnf_main<<<BATCH / 64, 512, SMEM_BYTES, stream>>>(x, eps, ws, out);
}